// Round 18
// baseline (164.062 us; speedup 1.0000x reference)
//
#include <hip/hip_runtime.h>

#define BDIM 256
#define NB 8
#define NC 192
#define NN 3136         // 56*56 = 49*64
#define NCH 384
#define NK 9
#define NROW (NB * NN)  // 25088

typedef __attribute__((ext_vector_type(8))) short short8;
typedef __attribute__((ext_vector_type(4))) float f32x4;

__device__ __forceinline__ unsigned short f2bf(float f) {
  union { float f; unsigned u; } x{f};
  unsigned r = x.u + 0x7fff + ((x.u >> 16) & 1);  // RNE
  return (unsigned short)(r >> 16);
}

__device__ __forceinline__ float bf2f(unsigned u16) {
  union { unsigned u; float f; } x{u16 << 16};
  return x.f;
}

__device__ __forceinline__ unsigned umax_(unsigned a, unsigned b) { return a > b ? a : b; }
__device__ __forceinline__ unsigned umin_(unsigned a, unsigned b) { return a < b ? a : b; }
#define UMAX3(a, b, c) umax_(umax_((a), (b)), (c))
#define CXD(x, y)                      \
  {                                    \
    unsigned h_ = umax_(x, y);         \
    unsigned l_ = umin_(x, y);         \
    x = h_;                            \
    y = l_;                            \
  }
// sort4 desc + exact (9,4) selection-merge into TK[0..8] (descending walk)
#define SEL94(TK, a0, a1, a2, a3)                                          \
  {                                                                        \
    CXD(a0, a1); CXD(a2, a3); CXD(a0, a2); CXD(a1, a3); CXD(a1, a2);       \
    TK[8] = UMAX3(UMAX3(TK[8], umin_(TK[7], a0), umin_(TK[6], a1)),        \
                  umin_(TK[5], a2), umin_(TK[4], a3));                     \
    TK[7] = UMAX3(UMAX3(TK[7], umin_(TK[6], a0), umin_(TK[5], a1)),        \
                  umin_(TK[4], a2), umin_(TK[3], a3));                     \
    TK[6] = UMAX3(UMAX3(TK[6], umin_(TK[5], a0), umin_(TK[4], a1)),        \
                  umin_(TK[3], a2), umin_(TK[2], a3));                     \
    TK[5] = UMAX3(UMAX3(TK[5], umin_(TK[4], a0), umin_(TK[3], a1)),        \
                  umin_(TK[2], a2), umin_(TK[1], a3));                     \
    TK[4] = UMAX3(UMAX3(TK[4], umin_(TK[3], a0), umin_(TK[2], a1)),        \
                  umin_(TK[1], a2), umin_(TK[0], a3));                     \
    TK[3] = UMAX3(UMAX3(TK[3], a3, umin_(TK[2], a0)),                      \
                  umin_(TK[1], a1), umin_(TK[0], a2));                     \
    TK[2] = umax_(UMAX3(TK[2], a2, umin_(TK[1], a0)), umin_(TK[0], a1));   \
    TK[1] = UMAX3(TK[1], a1, umin_(TK[0], a0));                            \
    TK[0] = umax_(TK[0], a0);                                              \
  }

// key for sim value f (in [-1,1]) and index term it: bits(f+2.0) is positive and
// bitwise-monotone in f; top 20 bits | (4095-m) gives value-then-lowest-index order.
__device__ __forceinline__ unsigned simkey(float f, unsigned it) {
  union { float f; unsigned u; } x{f + 2.0f};
  return (x.u & 0xFFFFF000u) | it;
}

__device__ __forceinline__ void gload16(const char* g, char* l) {
  __builtin_amdgcn_global_load_lds(
      (const __attribute__((address_space(1))) unsigned int*)g,
      (__attribute__((address_space(3))) unsigned int*)l, 16, 0, 0);
}

// stage one 24KB [64 rows][384B] bf16 tile into LDS (async, width 16), 256 thr,
// 6 loads/thread. LDS dest linear; global source pre-XOR-swizzled:
// LDS[m][kb] = G[m][kb ^ ((m&7)<<4)].
__device__ __forceinline__ void stage_tile(const char* gbase, char* lbuf, int t) {
#pragma unroll
  for (int i = 0; i < 6; ++i) {
    int L = (i * 256 + t) * 16;
    int m = L / 384;
    int kb = L - m * 384;
    gload16(gbase + m * 384 + (kb ^ ((m & 7) << 4)), lbuf + L);
  }
}

// 24KB tile staged by 512 threads: 3 loads/thread
__device__ __forceinline__ void stage64_512(const char* gbase, char* lbuf, int t) {
#pragma unroll
  for (int i = 0; i < 3; ++i) {
    int L = (i * 512 + t) * 16;
    int m = L / 384;
    int kb = L - m * 384;
    gload16(gbase + m * 384 + (kb ^ ((m & 7) << 4)), lbuf + L);
  }
}

// ---------- K0: bf16 weight conversion ----------
__global__ __launch_bounds__(BDIM) void k0_convw(
    const float* __restrict__ gw, const float* __restrict__ f1w,
    const float* __restrict__ f2w, unsigned short* __restrict__ gcwb,
    unsigned short* __restrict__ fc1b, unsigned short* __restrict__ fc2b) {
  int i = (blockIdx.x * BDIM + threadIdx.x) * 4;
  const float* src;
  unsigned short* dst;
  if (i < 147456) {  // gc_w split
    int o = i / NC, k = i - o * NC;
    src = gw + (size_t)(o < NCH ? o : o - NCH) * (2 * NC) + (o < NCH ? 0 : NC) + k;
    dst = gcwb + i;
  } else if (i < 184320) {  // fc1
    int j = i - 147456;
    src = f1w + j;
    dst = fc1b + j;
  } else {  // fc2 retile [(oc*2+kh)][64][192]
    int j = i - 184320;
    int o = j / NCH, k = j - o * NCH;
    int oc = o >> 6, om = o & 63;
    int kh = k / 192, km = k - kh * 192;
    src = f2w + j;
    dst = fc2b + ((size_t)((oc * 2 + kh) * 64 + om)) * 192 + km;
  }
  float4 v = *(const float4*)src;
  uint2 u;
  u.x = (unsigned)f2bf(v.x) | ((unsigned)f2bf(v.y) << 16);
  u.y = (unsigned)f2bf(v.z) | ((unsigned)f2bf(v.w) << 16);
  *(uint2*)dst = u;
}

// ---------- K0b: fold BN params: val = gemm*sc + sh ----------
__global__ __launch_bounds__(384) void k0b_params(
    const float* __restrict__ f1b, const float* __restrict__ g1,
    const float* __restrict__ b1, const float* __restrict__ m1,
    const float* __restrict__ v1, const float* __restrict__ gcb,
    const float* __restrict__ g2, const float* __restrict__ b2,
    const float* __restrict__ m2, const float* __restrict__ v2,
    const float* __restrict__ f2b, const float* __restrict__ g3,
    const float* __restrict__ b3, const float* __restrict__ m3,
    const float* __restrict__ v3, float* __restrict__ sc1,
    float* __restrict__ sh1, float* __restrict__ sc2, float* __restrict__ sh2,
    float* __restrict__ sc3, float* __restrict__ sh3) {
  int c = threadIdx.x;
  if (c < NC) {
    float s1 = g1[c] * rsqrtf(v1[c] + 1e-5f);
    sc1[c] = s1;
    sh1[c] = (f1b[c] - m1[c]) * s1 + b1[c];
    float s3 = g3[c] * rsqrtf(v3[c] + 1e-5f);
    sc3[c] = s3;
    sh3[c] = (f2b[c] - m3[c]) * s3 + b3[c];
  }
  float s2 = g2[c] * rsqrtf(v2[c] + 1e-5f);
  sc2[c] = s2;
  sh2[c] = (gcb[c] - m2[c]) * s2 + b2[c];
}

// ---------- K1: h = BN1(x @ fc1_w^T) via MFMA; x read directly (fused transpose) ----------
__global__ __launch_bounds__(BDIM) void k1_mfma(
    const float* __restrict__ x, const unsigned short* __restrict__ fc1b,
    const float* __restrict__ sc1, const float* __restrict__ sh1,
    unsigned short* __restrict__ hnb, float* __restrict__ normo) {
  __shared__ __align__(16) char abuf[2][24576];
  int t = threadIdx.x;
  int b = blockIdx.x / 49, n0 = (blockIdx.x % 49) * 64;
  int lane = t & 63, w = t >> 6;
  int l15 = lane & 15, l4 = lane >> 4;
  int n = n0 + w * 16 + l15;
  short8 bfr[6];
  {
    const float* xcol = x + (size_t)b * NC * NN + n;
#pragma unroll
    for (int ks = 0; ks < 6; ++ks) {
      union { short8 s; unsigned u[4]; } pk;
#pragma unroll
      for (int j = 0; j < 4; ++j) {
        float v0 = xcol[(size_t)(ks * 32 + l4 * 8 + 2 * j) * NN];
        float v1 = xcol[(size_t)(ks * 32 + l4 * 8 + 2 * j + 1) * NN];
        pk.u[j] = (unsigned)f2bf(v0) | ((unsigned)f2bf(v1) << 16);
      }
      bfr[ks] = pk.s;
    }
  }
  f32x4 acc[3][4];
#pragma unroll
  for (int oc = 0; oc < 3; ++oc)
#pragma unroll
    for (int sub = 0; sub < 4; ++sub) acc[oc][sub] = {0.f, 0.f, 0.f, 0.f};

  const char* wB = (const char*)fc1b;
  stage_tile(wB, abuf[0], t);
  __syncthreads();
  for (int oc = 0; oc < 3; ++oc) {
    int cur = oc & 1;
    if (oc < 2) stage_tile(wB + (size_t)(oc + 1) * 24576, abuf[cur ^ 1], t);
#pragma unroll
    for (int sub = 0; sub < 4; ++sub) {
      int r_ = sub * 16 + l15;
      int rbase = r_ * 384, sw = (r_ & 7) << 4;
#pragma unroll
      for (int ks = 0; ks < 6; ++ks) {
        short8 af = *(const short8*)&abuf[cur][rbase + ((ks * 64 + l4 * 16) ^ sw)];
        acc[oc][sub] = __builtin_amdgcn_mfma_f32_16x16x32_bf16(af, bfr[ks],
                                                               acc[oc][sub], 0, 0, 0);
      }
    }
    __syncthreads();
  }
  float p = 0.f;
#pragma unroll
  for (int oc = 0; oc < 3; ++oc)
#pragma unroll
    for (int sub = 0; sub < 4; ++sub) {
      int c4 = oc * 64 + sub * 16 + l4 * 4;
      float s_[4], h_[4];
      *(float4*)s_ = *(const float4*)&sc1[c4];
      *(float4*)h_ = *(const float4*)&sh1[c4];
#pragma unroll
      for (int r = 0; r < 4; ++r) {
        float v = acc[oc][sub][r] * s_[r] + h_[r];
        acc[oc][sub][r] = v;
        p += v * v;
      }
    }
  p += __shfl_xor(p, 16);
  p += __shfl_xor(p, 32);
  float nr = fmaxf(sqrtf(p), 1e-12f);
  float iv = 1.f / nr;
  if (l4 == 0) normo[(size_t)b * NN + n] = nr;
#pragma unroll
  for (int oc = 0; oc < 3; ++oc)
#pragma unroll
    for (int sub = 0; sub < 4; ++sub) {
      uint2 u;
      u.x = (unsigned)f2bf(acc[oc][sub][0] * iv) |
            ((unsigned)f2bf(acc[oc][sub][1] * iv) << 16);
      u.y = (unsigned)f2bf(acc[oc][sub][2] * iv) |
            ((unsigned)f2bf(acc[oc][sub][3] * iv) << 16);
      *(uint2*)&hnb[(size_t)(b * NN + n) * NC + oc * 64 + sub * 16 + l4 * 4] = u;
    }
}

// ---------- K23: fused 512-thr dispatch ----------
// k2a role: 64-row tiles (24KB), wave = (sub m-quarter) x (wgp n-half); each
// wave's af read feeds TWO n-group MFMAs -> LDS amplification 4x -> 2x.
// Counted vmcnt(3) double buffer. k3 role: R16's triple-12KB structure.
__global__ __launch_bounds__(512) void k23_fused(
    const unsigned short* __restrict__ hnb, const float* __restrict__ norm,
    const unsigned short* __restrict__ gcwb, unsigned* __restrict__ candK,
    unsigned short* __restrict__ P, unsigned short* __restrict__ Q) {
  __shared__ __align__(16) char abuf[49152];
  int t = threadIdx.x;
  int bid = blockIdx.x;
  int b = bid & 7;          // batch == XCD
  int j = bid >> 3;         // 0..244 per XCD
  int lane = t & 63, w = t >> 6;
  int l15 = lane & 15, l4 = lane >> 4;
  const unsigned short* hb = hnb + (size_t)b * NN * NC;

  if (j % 5 != 4) {
    // ---- k2a role: 196 blocks/XCD; 64 n x quarter-m; 2 n-groups per wave ----
    int idx2a = (j / 5) * 4 + (j % 5);  // 0..195
    int n0 = (idx2a >> 2) * 64;
    int seg = idx2a & 3;
    int mt0 = (49 * seg) / 4, mt1 = (49 * (seg + 1)) / 4;  // 64-row tiles
    const char* hbB = (const char*)hb;
    int wgp = w & 1, sub = w >> 1;  // n-half, m-quarter

    // B frags for 2 n-groups: n = n0 + (2*wgp+gg)*16 + l15, k = ks*32 + l4*8 + j
    short8 bfrA[6], bfrB[6];
    {
      const short8* ra =
          (const short8*)(hb + (size_t)(n0 + wgp * 32 + l15) * NC + l4 * 8);
      const short8* rb =
          (const short8*)(hb + (size_t)(n0 + wgp * 32 + 16 + l15) * NC + l4 * 8);
#pragma unroll
      for (int ks = 0; ks < 6; ++ks) { bfrA[ks] = ra[ks * 4]; bfrB[ks] = rb[ks * 4]; }
    }
    // A frag ds_read offsets: row = sub*16 + l15 within 64-row tile
    int r_ = sub * 16 + l15;
    int rbase = r_ * 384, sw = (r_ & 7) << 4;
    int dso[6];
#pragma unroll
    for (int ks = 0; ks < 6; ++ks) dso[ks] = rbase + ((ks * 64 + l4 * 16) ^ sw);

    unsigned tkA[NK], tkB[NK];
#pragma unroll
    for (int r = 0; r < NK; ++r) { tkA[r] = 0u; tkB[r] = 0u; }

    stage64_512(hbB + (size_t)mt0 * 24576, abuf, t);
    int nt = mt1 - mt0;
    int cur = 0;
    for (int ti = 0; ti < nt; ++ti) {
      if (ti + 1 < nt) {
        stage64_512(hbB + (size_t)(mt0 + ti + 1) * 24576, abuf + (cur ^ 1) * 24576, t);
        asm volatile("s_waitcnt vmcnt(3)" ::: "memory");
      } else {
        asm volatile("s_waitcnt vmcnt(0)" ::: "memory");
      }
      __builtin_amdgcn_s_barrier();
      __builtin_amdgcn_sched_barrier(0);
      const char* lb = abuf + cur * 24576;
      short8 af[6];
#pragma unroll
      for (int ks = 0; ks < 6; ++ks) af[ks] = *(const short8*)&lb[dso[ks]];
      f32x4 accA = {0.f, 0.f, 0.f, 0.f};
      f32x4 accB = {0.f, 0.f, 0.f, 0.f};
#pragma unroll
      for (int ks = 0; ks < 6; ++ks) {
        accA = __builtin_amdgcn_mfma_f32_16x16x32_bf16(af[ks], bfrA[ks], accA, 0, 0, 0);
        accB = __builtin_amdgcn_mfma_f32_16x16x32_bf16(af[ks], bfrB[ks], accB, 0, 0, 0);
      }
      unsigned mknd = (unsigned)(4095 - ((mt0 + ti) * 64 + sub * 16 + l4 * 4));
      {
        unsigned c0 = simkey(accA[0], mknd);
        unsigned c1 = simkey(accA[1], mknd - 1);
        unsigned c2 = simkey(accA[2], mknd - 2);
        unsigned c3 = simkey(accA[3], mknd - 3);
        SEL94(tkA, c0, c1, c2, c3);
      }
      {
        unsigned c0 = simkey(accB[0], mknd);
        unsigned c1 = simkey(accB[1], mknd - 1);
        unsigned c2 = simkey(accB[2], mknd - 2);
        unsigned c3 = simkey(accB[3], mknd - 3);
        SEL94(tkB, c0, c1, c2, c3);
      }
      __builtin_amdgcn_sched_barrier(0);
      __builtin_amdgcn_s_barrier();  // reads of buf[cur] done before re-stage
      cur ^= 1;
    }
    // merge 16 lists per n-row: [64 rows][16 lists][9] = 36KB (aliases abuf)
    unsigned* mkeys = (unsigned*)abuf;
    int slot = sub * 4 + l4;
    int rowA = wgp * 32 + l15, rowB = wgp * 32 + 16 + l15;
#pragma unroll
    for (int r = 0; r < NK; ++r) {
      mkeys[(rowA * 16 + slot) * NK + r] = tkA[r];
      mkeys[(rowB * 16 + slot) * NK + r] = tkB[r];
    }
    __syncthreads();
    if (t < 256) {  // stage 2: merge lists q*4..q*4+3 -> list q*4
      int row = t >> 2, q = t & 3;
      unsigned* a = &mkeys[(row * 16 + q * 4) * NK];
      unsigned best[NK];
#pragma unroll
      for (int r = 0; r < NK; ++r) best[r] = 0u;
      for (int s = 0; s < 36; ++s) {
        unsigned cur_k = a[s];
#pragma unroll
        for (int q2 = 0; q2 < NK; ++q2) {
          unsigned hi = best[q2] > cur_k ? best[q2] : cur_k;
          unsigned lo = best[q2] > cur_k ? cur_k : best[q2];
          best[q2] = hi;
          cur_k = lo;
        }
      }
#pragma unroll
      for (int r = 0; r < NK; ++r) a[r] = best[r];
    }
    __syncthreads();
    if (t < 64) {  // stage 3: merge lists 0,4,8,12 (36 keys)
      const unsigned* base = &mkeys[t * 16 * NK];
      unsigned best[NK];
#pragma unroll
      for (int r = 0; r < NK; ++r) best[r] = 0u;
#pragma unroll
      for (int q = 0; q < 4; ++q)
        for (int s = 0; s < NK; ++s) {
          unsigned cur_k = base[q * 36 + s];
#pragma unroll
          for (int q2 = 0; q2 < NK; ++q2) {
            unsigned hi = best[q2] > cur_k ? best[q2] : cur_k;
            unsigned lo = best[q2] > cur_k ? cur_k : best[q2];
            best[q2] = hi;
            cur_k = lo;
          }
        }
      size_t rowg = (size_t)b * NN + n0 + t;
#pragma unroll
      for (int r = 0; r < NK; ++r)
        candK[(size_t)(seg * NK + r) * NROW + rowg] = best[r];
    }
  } else {
    // ---- k3 role: 49 blocks/XCD; P,Q = bf16((hn @ gcwb^T) * norm), 24 chunks ----
    // triple 12KB buffers, one barrier per chunk (R16 structure)
    int jj = j / 5;  // 0..48
    int n0 = jj * 64;
    int wg = w & 3, sub = w >> 2;
    int n = n0 + wg * 16 + l15;
    short8 bfr[6];
    {
      const short8* brow = (const short8*)(hb + (size_t)n * NC + l4 * 8);
#pragma unroll
      for (int ks = 0; ks < 6; ++ks) bfr[ks] = brow[ks * 4];
    }
    float nrm = norm[(size_t)b * NN + n];
    size_t orow = (size_t)b * NN + n;
    const char* wB = (const char*)gcwb;

    // hoisted staging offsets (waves 0-5 only: 2 lines/thread)
    int LA = t * 16;
    int mA = LA / 384, kbA = LA - mA * 384;
    int gA = mA * 384 + (kbA ^ ((mA & 7) << 4));
    int LB = (384 + t) * 16;
    int mB = LB / 384, kbB = LB - mB * 384;
    int gB = mB * 384 + (kbB ^ ((mB & 7) << 4));
    bool stg = (t < 384);
    int r_ = sub * 16 + l15;
    int rbase = r_ * 384, sw = (r_ & 7) << 4;
    int dso[6];
#pragma unroll
    for (int ks = 0; ks < 6; ++ks) dso[ks] = rbase + ((ks * 64 + l4 * 16) ^ sw);

    if (stg) { gload16(wB + gA, abuf + LA); gload16(wB + gB, abuf + LB); }
    int cur = 0;
    for (int ch = 0; ch < 24; ++ch) {
      int nxt = cur + 1 == 3 ? 0 : cur + 1;
      if (ch < 23) {
        const char* src = wB + (size_t)(ch + 1) * 12288;
        char* dl = abuf + nxt * 12288;
        if (stg) { gload16(src + gA, dl + LA); gload16(src + gB, dl + LB); }
        asm volatile("s_waitcnt vmcnt(3)" ::: "memory");  // tolerate 1 store in flight
      } else {
        asm volatile("s_waitcnt vmcnt(0)" ::: "memory");
      }
      __builtin_amdgcn_s_barrier();
      __builtin_amdgcn_sched_barrier(0);
      const char* lb = abuf + cur * 12288;
      f32x4 acc = {0.f, 0.f, 0.f, 0.f};
#pragma unroll
      for (int ks = 0; ks < 6; ++ks) {
        short8 af = *(const short8*)&lb[dso[ks]];
        acc = __builtin_amdgcn_mfma_f32_16x16x32_bf16(af, bfr[ks], acc, 0, 0, 0);
      }
      int o = ch * 32 + sub * 16 + l4 * 4;
      f32x4 st = acc * nrm;
      unsigned short* dst = (o < NCH) ? P : Q;
      int oo = (o < NCH) ? o : o - NCH;
      uint2 u;
      u.x = (unsigned)f2bf(st[0]) | ((unsigned)f2bf(st[1]) << 16);
      u.y = (unsigned)f2bf(st[2]) | ((unsigned)f2bf(st[3]) << 16);
      *(uint2*)&dst[orow * NCH + oo] = u;
      cur = nxt;
    }
  }
}

// ---------- K2b: merge 4x9 keys/row -> final top-9 indices ----------
__global__ __launch_bounds__(BDIM) void k2b_merge(const unsigned* __restrict__ candK,
                                                  int* __restrict__ idxo) {
  int row = blockIdx.x * BDIM + threadIdx.x;
  unsigned tk[NK];
#pragma unroll
  for (int r = 0; r < NK; ++r) tk[r] = 0u;
  for (int s = 0; s < 4 * NK; ++s) {
    unsigned cur = candK[(size_t)s * NROW + row];
#pragma unroll
    for (int j = 0; j < NK; ++j) {
      unsigned hi = tk[j] > cur ? tk[j] : cur;
      unsigned lo = tk[j] > cur ? cur : tk[j];
      tk[j] = hi;
      cur = lo;
    }
  }
#pragma unroll
  for (int r = 0; r < NK; ++r)
    idxo[(size_t)row * NK + r] = 4095 - (int)(tk[r] & 4095u);
}

// ---------- K4: batch->XCD-pinned gather-max + BN2 + gelu, bf16 out ----------
__global__ __launch_bounds__(BDIM) void k4_gathermax(
    const unsigned short* __restrict__ P, const unsigned short* __restrict__ Q,
    const int* __restrict__ idx, const float* __restrict__ sc2,
    const float* __restrict__ sh2, unsigned short* __restrict__ mbh) {
  int t = threadIdx.x;
  int lane = t & 63, wv = t >> 6;
  int b = blockIdx.x & 7;                      // batch == XCD (L2 pin for Q slab)
  int n = (int)(blockIdx.x >> 3) * 4 + wv;     // 0..3135
  size_t row = (size_t)b * NN + n;
  const int* ip = idx + row * NK;
  int id[NK];
#pragma unroll
  for (int k = 0; k < NK; ++k) id[k] = ip[k];
  const unsigned short* Qb = Q + (size_t)b * NN * NCH;
  const unsigned short* Pr = P + row * NCH;
  const unsigned short* Qr = Qb + (size_t)n * NCH;
#pragma unroll
  for (int j = 0; j < 3; ++j) {
    int o = j * 128 + lane * 2;
    float mx0 = -1e30f, mx1 = -1e30f;
#pragma unroll
    for (int k = 0; k < NK; ++k) {
      unsigned g = *(const unsigned*)&Qb[(size_t)id[k] * NCH + o];
      mx0 = fmaxf(mx0, bf2f(g & 0xffffu));
      mx1 = fmaxf(mx1, bf2f(g >> 16));
    }
    unsigned pv = *(const unsigned*)&Pr[o];
    unsigned qv = *(const unsigned*)&Qr[o];
    float2 ss = *(const float2*)&sc2[o];
    float2 hh = *(const float2*)&sh2[o];
    float e0 = bf2f(pv & 0xffffu) - bf2f(qv & 0xffffu) + mx0;
    float e1 = bf2f(pv >> 16) - bf2f(qv >> 16) + mx1;
    float y0 = e0 * ss.x + hh.x;
    float y1 = e1 * ss.y + hh.y;
    float ge0 = 0.5f * y0 * (1.f + erff(y0 * 0.70710678118654752f));
    float ge1 = 0.5f * y1 * (1.f + erff(y1 * 0.70710678118654752f));
    *(unsigned*)&mbh[row * NCH + o] =
        (unsigned)f2bf(ge0) | ((unsigned)f2bf(ge1) << 16);
  }
}

// ---------- K5: out = BN3(m @ fc2_w^T) + x via MFMA, direct [c][n] store ----------
__global__ __launch_bounds__(BDIM) void k5_mfma(
    const unsigned short* __restrict__ mbh, const unsigned short* __restrict__ fc2b,
    const float* __restrict__ sc3, const float* __restrict__ sh3,
    const float* __restrict__ x, float* __restrict__ out) {
  __shared__ __align__(16) char abuf[2][24576];
  int t = threadIdx.x;
  int bid = blockIdx.x;
  int b = bid / 147;
  int rem = bid % 147;
  int n0 = (rem / 3) * 64;
  int oc = rem % 3;
  int lane = t & 63, w = t >> 6;
  int l15 = lane & 15, l4 = lane >> 4;
  int n = n0 + w * 16 + l15;
  short8 bfr[12];
  {
    const short8* brow = (const short8*)(mbh + (size_t)(b * NN + n) * NCH + l4 * 8);
#pragma unroll
    for (int kh = 0; kh < 2; ++kh)
#pragma unroll
      for (int ks = 0; ks < 6; ++ks) bfr[kh * 6 + ks] = brow[kh * 24 + ks * 4];
  }
  f32x4 acc[4];
#pragma unroll
  for (int sub = 0; sub < 4; ++sub) acc[sub] = {0.f, 0.f, 0.f, 0.f};

  const char* wt = (const char*)fc2b + (size_t)oc * 2 * 24576;
  stage_tile(wt, abuf[0], t);
  __syncthreads();
  for (int kh = 0; kh < 2; ++kh) {
    if (kh == 0) stage_tile(wt + 24576, abuf[1], t);
#pragma unroll
    for (int sub = 0; sub < 4; ++sub) {
      int r_ = sub * 16 + l15;
      int rbase = r_ * 384, sw = (r_ & 7) << 4;
#pragma unroll
      for (int ks = 0; ks < 6; ++ks) {
        short8 af = *(const short8*)&abuf[kh][rbase + ((ks * 64 + l4 * 16) ^ sw)];
        acc[sub] = __builtin_amdgcn_mfma_f32_16x16x32_bf16(af, bfr[kh * 6 + ks],
                                                           acc[sub], 0, 0, 0);
      }
    }
    __syncthreads();
  }
  const float* xb_ = x + (size_t)b * NC * NN;
  float* ob = out + (size_t)b * NC * NN;
#pragma unroll
  for (int sub = 0; sub < 4; ++sub) {
    int c4 = oc * 64 + sub * 16 + l4 * 4;
    float s_[4], h_[4];
    *(float4*)s_ = *(const float4*)&sc3[c4];
    *(float4*)h_ = *(const float4*)&sh3[c4];
#pragma unroll
    for (int r = 0; r < 4; ++r) {
      size_t off = (size_t)(c4 + r) * NN + n;
      ob[off] = acc[sub][r] * s_[r] + h_[r] + xb_[off];
    }
  }
}

extern "C" void kernel_launch(void* const* d_in, const int* in_sizes, int n_in,
                              void* d_out, int out_size, void* d_ws, size_t ws_size,
                              hipStream_t stream) {
  const float* x = (const float*)d_in[0];
  const float* fc1_w = (const float*)d_in[1];
  const float* fc1_b = (const float*)d_in[2];
  const float* bn1_g = (const float*)d_in[3];
  const float* bn1_b = (const float*)d_in[4];
  const float* bn1_m = (const float*)d_in[5];
  const float* bn1_v = (const float*)d_in[6];
  const float* gc_w = (const float*)d_in[7];
  const float* gc_b = (const float*)d_in[8];
  const float* bn2_g = (const float*)d_in[9];
  const float* bn2_b = (const float*)d_in[10];
  const float* bn2_m = (const float*)d_in[11];
  const float* bn2_v = (const float*)d_in[12];
  const float* fc2_w = (const float*)d_in[13];
  const float* fc2_b = (const float*)d_in[14];
  const float* bn3_g = (const float*)d_in[15];
  const float* bn3_b = (const float*)d_in[16];
  const float* bn3_m = (const float*)d_in[17];
  const float* bn3_v = (const float*)d_in[18];

  size_t nrow = (size_t)NROW;
  size_t npq = (size_t)NB * NN * NCH;
  size_t nhb = (size_t)NB * NN * NC;
  unsigned short* Pb = (unsigned short*)d_ws;
  unsigned short* Qb = Pb + npq;
  unsigned short* mbh = Qb + npq;
  float* norm = (float*)(mbh + npq);
  int* idx = (int*)(norm + nrow);
  unsigned short* hnb = (unsigned short*)(idx + nrow * NK);
  unsigned short* gcwb = hnb + nhb;
  unsigned short* fc1b = gcwb + 768 * NC;
  unsigned short* fc2b = fc1b + NC * NC;
  unsigned* candK = (unsigned*)(fc2b + NC * NCH);
  float* sc1 = (float*)(candK + 4 * NK * nrow);
  float* sh1 = sc1 + NC;
  float* sc2 = sh1 + NC;
  float* sh2 = sc2 + NCH;
  float* sc3 = sh2 + NCH;
  float* sh3 = sc3 + NC;

  k0_convw<<<252, BDIM, 0, stream>>>(gc_w, fc1_w, fc2_w, gcwb, fc1b, fc2b);
  k0b_params<<<1, 384, 0, stream>>>(fc1_b, bn1_g, bn1_b, bn1_m, bn1_v, gc_b,
                                    bn2_g, bn2_b, bn2_m, bn2_v, fc2_b, bn3_g,
                                    bn3_b, bn3_m, bn3_v, sc1, sh1, sc2, sh2,
                                    sc3, sh3);
  k1_mfma<<<NB * 49, BDIM, 0, stream>>>(x, fc1b, sc1, sh1, hnb, norm);
  k23_fused<<<NB * 245, 512, 0, stream>>>(hnb, norm, gcwb, candK, Pb, Qb);
  k2b_merge<<<NROW / BDIM, BDIM, 0, stream>>>(candK, idx);
  k4_gathermax<<<(NB * NN) / 4, BDIM, 0, stream>>>(Pb, Qb, idx, sc2, sh2, mbh);
  k5_mfma<<<NB * 147, BDIM, 0, stream>>>(mbh, fc2b, sc3, sh3, x, (float*)d_out);
}

// Round 19
// 144.865 us; speedup vs baseline: 1.1325x; 1.1325x over previous
//
#include <hip/hip_runtime.h>

#define BDIM 256
#define NB 8
#define NC 192
#define NN 3136         // 56*56 = 49*64
#define NCH 384
#define NK 9
#define NROW (NB * NN)  // 25088

typedef __attribute__((ext_vector_type(8))) short short8;
typedef __attribute__((ext_vector_type(4))) float f32x4;

__device__ __forceinline__ unsigned short f2bf(float f) {
  union { float f; unsigned u; } x{f};
  unsigned r = x.u + 0x7fff + ((x.u >> 16) & 1);  // RNE
  return (unsigned short)(r >> 16);
}

__device__ __forceinline__ float bf2f(unsigned u16) {
  union { unsigned u; float f; } x{u16 << 16};
  return x.f;
}

__device__ __forceinline__ unsigned umax_(unsigned a, unsigned b) { return a > b ? a : b; }
__device__ __forceinline__ unsigned umin_(unsigned a, unsigned b) { return a < b ? a : b; }
#define UMAX3(a, b, c) umax_(umax_((a), (b)), (c))
#define CXD(x, y)                      \
  {                                    \
    unsigned h_ = umax_(x, y);         \
    unsigned l_ = umin_(x, y);         \
    x = h_;                            \
    y = l_;                            \
  }

// key for sim value f (in [-1,1]) and index term it: bits(f+2.0) is positive and
// bitwise-monotone in f; top 20 bits | (4095-m) gives value-then-lowest-index order.
__device__ __forceinline__ unsigned simkey(float f, unsigned it) {
  union { float f; unsigned u; } x{f + 2.0f};
  return (x.u & 0xFFFFF000u) | it;
}

__device__ __forceinline__ void gload16(const char* g, char* l) {
  __builtin_amdgcn_global_load_lds(
      (const __attribute__((address_space(1))) unsigned int*)g,
      (__attribute__((address_space(3))) unsigned int*)l, 16, 0, 0);
}

// stage one 24KB [64 rows][384B] bf16 tile into LDS (async, width 16), 256 thr.
// LDS dest linear; global source pre-XOR-swizzled: LDS[m][kb] = G[m][kb^((m&7)<<4)].
__device__ __forceinline__ void stage_tile(const char* gbase, char* lbuf, int t) {
#pragma unroll
  for (int i = 0; i < 6; ++i) {
    int L = (i * 256 + t) * 16;
    int m = L / 384;
    int kb = L - m * 384;
    gload16(gbase + m * 384 + (kb ^ ((m & 7) << 4)), lbuf + L);
  }
}

// ---------- K0: bf16 weight conversion ----------
__global__ __launch_bounds__(BDIM) void k0_convw(
    const float* __restrict__ gw, const float* __restrict__ f1w,
    const float* __restrict__ f2w, unsigned short* __restrict__ gcwb,
    unsigned short* __restrict__ fc1b, unsigned short* __restrict__ fc2b) {
  int i = (blockIdx.x * BDIM + threadIdx.x) * 4;
  const float* src;
  unsigned short* dst;
  if (i < 147456) {  // gc_w split
    int o = i / NC, k = i - o * NC;
    src = gw + (size_t)(o < NCH ? o : o - NCH) * (2 * NC) + (o < NCH ? 0 : NC) + k;
    dst = gcwb + i;
  } else if (i < 184320) {  // fc1
    int j = i - 147456;
    src = f1w + j;
    dst = fc1b + j;
  } else {  // fc2 retile [(oc*2+kh)][64][192]
    int j = i - 184320;
    int o = j / NCH, k = j - o * NCH;
    int oc = o >> 6, om = o & 63;
    int kh = k / 192, km = k - kh * 192;
    src = f2w + j;
    dst = fc2b + ((size_t)((oc * 2 + kh) * 64 + om)) * 192 + km;
  }
  float4 v = *(const float4*)src;
  uint2 u;
  u.x = (unsigned)f2bf(v.x) | ((unsigned)f2bf(v.y) << 16);
  u.y = (unsigned)f2bf(v.z) | ((unsigned)f2bf(v.w) << 16);
  *(uint2*)dst = u;
}

// ---------- K0b: fold BN params: val = gemm*sc + sh ----------
__global__ __launch_bounds__(384) void k0b_params(
    const float* __restrict__ f1b, const float* __restrict__ g1,
    const float* __restrict__ b1, const float* __restrict__ m1,
    const float* __restrict__ v1, const float* __restrict__ gcb,
    const float* __restrict__ g2, const float* __restrict__ b2,
    const float* __restrict__ m2, const float* __restrict__ v2,
    const float* __restrict__ f2b, const float* __restrict__ g3,
    const float* __restrict__ b3, const float* __restrict__ m3,
    const float* __restrict__ v3, float* __restrict__ sc1,
    float* __restrict__ sh1, float* __restrict__ sc2, float* __restrict__ sh2,
    float* __restrict__ sc3, float* __restrict__ sh3) {
  int c = threadIdx.x;
  if (c < NC) {
    float s1 = g1[c] * rsqrtf(v1[c] + 1e-5f);
    sc1[c] = s1;
    sh1[c] = (f1b[c] - m1[c]) * s1 + b1[c];
    float s3 = g3[c] * rsqrtf(v3[c] + 1e-5f);
    sc3[c] = s3;
    sh3[c] = (f2b[c] - m3[c]) * s3 + b3[c];
  }
  float s2 = g2[c] * rsqrtf(v2[c] + 1e-5f);
  sc2[c] = s2;
  sh2[c] = (gcb[c] - m2[c]) * s2 + b2[c];
}

// ---------- K1: h = BN1(x @ fc1_w^T) via MFMA; x read directly (fused transpose) ----------
__global__ __launch_bounds__(BDIM) void k1_mfma(
    const float* __restrict__ x, const unsigned short* __restrict__ fc1b,
    const float* __restrict__ sc1, const float* __restrict__ sh1,
    unsigned short* __restrict__ hnb, float* __restrict__ normo) {
  __shared__ __align__(16) char abuf[2][24576];
  int t = threadIdx.x;
  int b = blockIdx.x / 49, n0 = (blockIdx.x % 49) * 64;
  int lane = t & 63, w = t >> 6;
  int l15 = lane & 15, l4 = lane >> 4;
  int n = n0 + w * 16 + l15;
  short8 bfr[6];
  {
    const float* xcol = x + (size_t)b * NC * NN + n;
#pragma unroll
    for (int ks = 0; ks < 6; ++ks) {
      union { short8 s; unsigned u[4]; } pk;
#pragma unroll
      for (int j = 0; j < 4; ++j) {
        float v0 = xcol[(size_t)(ks * 32 + l4 * 8 + 2 * j) * NN];
        float v1 = xcol[(size_t)(ks * 32 + l4 * 8 + 2 * j + 1) * NN];
        pk.u[j] = (unsigned)f2bf(v0) | ((unsigned)f2bf(v1) << 16);
      }
      bfr[ks] = pk.s;
    }
  }
  f32x4 acc[3][4];
#pragma unroll
  for (int oc = 0; oc < 3; ++oc)
#pragma unroll
    for (int sub = 0; sub < 4; ++sub) acc[oc][sub] = {0.f, 0.f, 0.f, 0.f};

  const char* wB = (const char*)fc1b;
  stage_tile(wB, abuf[0], t);
  __syncthreads();
  for (int oc = 0; oc < 3; ++oc) {
    int cur = oc & 1;
    if (oc < 2) stage_tile(wB + (size_t)(oc + 1) * 24576, abuf[cur ^ 1], t);
#pragma unroll
    for (int sub = 0; sub < 4; ++sub) {
      int r_ = sub * 16 + l15;
      int rbase = r_ * 384, sw = (r_ & 7) << 4;
#pragma unroll
      for (int ks = 0; ks < 6; ++ks) {
        short8 af = *(const short8*)&abuf[cur][rbase + ((ks * 64 + l4 * 16) ^ sw)];
        acc[oc][sub] = __builtin_amdgcn_mfma_f32_16x16x32_bf16(af, bfr[ks],
                                                               acc[oc][sub], 0, 0, 0);
      }
    }
    __syncthreads();
  }
  float p = 0.f;
#pragma unroll
  for (int oc = 0; oc < 3; ++oc)
#pragma unroll
    for (int sub = 0; sub < 4; ++sub) {
      int c4 = oc * 64 + sub * 16 + l4 * 4;
      float s_[4], h_[4];
      *(float4*)s_ = *(const float4*)&sc1[c4];
      *(float4*)h_ = *(const float4*)&sh1[c4];
#pragma unroll
      for (int r = 0; r < 4; ++r) {
        float v = acc[oc][sub][r] * s_[r] + h_[r];
        acc[oc][sub][r] = v;
        p += v * v;
      }
    }
  p += __shfl_xor(p, 16);
  p += __shfl_xor(p, 32);
  float nr = fmaxf(sqrtf(p), 1e-12f);
  float iv = 1.f / nr;
  if (l4 == 0) normo[(size_t)b * NN + n] = nr;
#pragma unroll
  for (int oc = 0; oc < 3; ++oc)
#pragma unroll
    for (int sub = 0; sub < 4; ++sub) {
      uint2 u;
      u.x = (unsigned)f2bf(acc[oc][sub][0] * iv) |
            ((unsigned)f2bf(acc[oc][sub][1] * iv) << 16);
      u.y = (unsigned)f2bf(acc[oc][sub][2] * iv) |
            ((unsigned)f2bf(acc[oc][sub][3] * iv) << 16);
      *(uint2*)&hnb[(size_t)(b * NN + n) * NC + oc * 64 + sub * 16 + l4 * 4] = u;
    }
}

// ---------- K23: fused 512-thr dispatch; TRIPLE buffer, ONE barrier per tile ----------
// stage(t+1)->buf[(t+1)%3] writes the buffer read at iter t-2; barrier chain makes
// the trailing barrier redundant. vmcnt(2) k2a / vmcnt(3) k3 (1 store in flight).
__global__ __launch_bounds__(512) void k23_fused(
    const unsigned short* __restrict__ hnb, const float* __restrict__ norm,
    const unsigned short* __restrict__ gcwb, unsigned* __restrict__ candK,
    unsigned short* __restrict__ P, unsigned short* __restrict__ Q) {
  __shared__ __align__(16) char abuf[3][12288];
  int t = threadIdx.x;
  int bid = blockIdx.x;
  int b = bid & 7;          // batch == XCD
  int j = bid >> 3;         // 0..244 per XCD
  int lane = t & 63, w = t >> 6;
  int l15 = lane & 15, l4 = lane >> 4;
  int wg = w & 3, sub = w >> 2;
  const unsigned short* hb = hnb + (size_t)b * NN * NC;

  // hoisted staging offsets (waves 0-5 only: 2 lines/thread)
  int LA = t * 16;
  int mA = LA / 384, kbA = LA - mA * 384;
  int gA = mA * 384 + (kbA ^ ((mA & 7) << 4));
  int LB = (384 + t) * 16;
  int mB = LB / 384, kbB = LB - mB * 384;
  int gB = mB * 384 + (kbB ^ ((mB & 7) << 4));
  bool stg = (t < 384);
  // hoisted ds_read offsets for this lane's sub-row
  int r_ = sub * 16 + l15;
  int rbase = r_ * 384, sw = (r_ & 7) << 4;
  int dso[6];
#pragma unroll
  for (int ks = 0; ks < 6; ++ks) dso[ks] = rbase + ((ks * 64 + l4 * 16) ^ sw);

  if (j % 5 != 4) {
    // ---- k2a role: 196 blocks/XCD; 64 n x quarter-m top-9 candidates ----
    int idx2a = (j / 5) * 4 + (j % 5);  // 0..195
    int n0 = (idx2a >> 2) * 64;
    int seg = idx2a & 3;
    int mt0 = (98 * seg) / 4, mt1 = (98 * (seg + 1)) / 4;  // 32-row tiles
    const char* hbB = (const char*)hb;

    short8 bfr[6];
    {
      const short8* brow =
          (const short8*)(hb + (size_t)(n0 + wg * 16 + l15) * NC + l4 * 8);
#pragma unroll
      for (int ks = 0; ks < 6; ++ks) bfr[ks] = brow[ks * 4];
    }
    unsigned tk[NK];
#pragma unroll
    for (int r = 0; r < NK; ++r) tk[r] = 0u;

    {
      const char* src = hbB + (size_t)mt0 * 12288;
      if (stg) { gload16(src + gA, abuf[0] + LA); gload16(src + gB, abuf[0] + LB); }
    }
    int nt = mt1 - mt0;
    int cur = 0;
    for (int ti = 0; ti < nt; ++ti) {
      int nxt = cur + 1 == 3 ? 0 : cur + 1;
      if (ti + 1 < nt) {
        const char* src = hbB + (size_t)(mt0 + ti + 1) * 12288;
        char* dl = &abuf[nxt][0];
        if (stg) { gload16(src + gA, dl + LA); gload16(src + gB, dl + LB); }
        asm volatile("s_waitcnt vmcnt(2)" ::: "memory");
      } else {
        asm volatile("s_waitcnt vmcnt(0)" ::: "memory");
      }
      __builtin_amdgcn_s_barrier();
      __builtin_amdgcn_sched_barrier(0);
      const char* lb = &abuf[cur][0];
      short8 af[6];
#pragma unroll
      for (int ks = 0; ks < 6; ++ks) af[ks] = *(const short8*)&lb[dso[ks]];
      f32x4 acc = {0.f, 0.f, 0.f, 0.f};
#pragma unroll
      for (int ks = 0; ks < 6; ++ks)
        acc = __builtin_amdgcn_mfma_f32_16x16x32_bf16(af[ks], bfr[ks], acc, 0, 0, 0);
      unsigned mknd = (unsigned)(4095 - ((mt0 + ti) * 32 + sub * 16 + l4 * 4));
      unsigned c0 = simkey(acc[0], mknd);
      unsigned c1 = simkey(acc[1], mknd - 1);
      unsigned c2 = simkey(acc[2], mknd - 2);
      unsigned c3 = simkey(acc[3], mknd - 3);
      // sort4 descending (5 comparators)
      CXD(c0, c1); CXD(c2, c3); CXD(c0, c2); CXD(c1, c3); CXD(c1, c2);
      // exact (9,4) selection-merge, descending (step j reads only lower indices)
      tk[8] = UMAX3(UMAX3(tk[8], umin_(tk[7], c0), umin_(tk[6], c1)),
                    umin_(tk[5], c2), umin_(tk[4], c3));
      tk[7] = UMAX3(UMAX3(tk[7], umin_(tk[6], c0), umin_(tk[5], c1)),
                    umin_(tk[4], c2), umin_(tk[3], c3));
      tk[6] = UMAX3(UMAX3(tk[6], umin_(tk[5], c0), umin_(tk[4], c1)),
                    umin_(tk[3], c2), umin_(tk[2], c3));
      tk[5] = UMAX3(UMAX3(tk[5], umin_(tk[4], c0), umin_(tk[3], c1)),
                    umin_(tk[2], c2), umin_(tk[1], c3));
      tk[4] = UMAX3(UMAX3(tk[4], umin_(tk[3], c0), umin_(tk[2], c1)),
                    umin_(tk[1], c2), umin_(tk[0], c3));
      tk[3] = UMAX3(UMAX3(tk[3], c3, umin_(tk[2], c0)),
                    umin_(tk[1], c1), umin_(tk[0], c2));
      tk[2] = umax_(UMAX3(tk[2], c2, umin_(tk[1], c0)), umin_(tk[0], c1));
      tk[1] = UMAX3(tk[1], c1, umin_(tk[0], c0));
      tk[0] = umax_(tk[0], c0);
      cur = nxt;
    }
    __syncthreads();  // loop exit is unsynced; abuf reused as merge scratch below
    // merge 8 lists per n-row: [64 rows][8 lists][9] = 18KB (aliases abuf)
    unsigned* mkeys = (unsigned*)&abuf[0][0];
    int rw = wg * 16 + l15;
#pragma unroll
    for (int r = 0; r < NK; ++r) mkeys[(rw * 8 + sub * 4 + l4) * NK + r] = tk[r];
    __syncthreads();
    if (t < 256) {  // stage 2: merge list pairs {g, g+4} -> list g
      int row = t >> 2, g = t & 3;
      unsigned* a = &mkeys[(row * 8 + g) * NK];
      const unsigned* c = &mkeys[(row * 8 + g + 4) * NK];
      unsigned best[NK];
#pragma unroll
      for (int r = 0; r < NK; ++r) best[r] = 0u;
#pragma unroll
      for (int s = 0; s < 2 * NK; ++s) {
        unsigned cur_k = s < NK ? a[s] : c[s - NK];
#pragma unroll
        for (int q = 0; q < NK; ++q) {
          unsigned hi = best[q] > cur_k ? best[q] : cur_k;
          unsigned lo = best[q] > cur_k ? cur_k : best[q];
          best[q] = hi;
          cur_k = lo;
        }
      }
#pragma unroll
      for (int r = 0; r < NK; ++r) a[r] = best[r];
    }
    __syncthreads();
    if (t < 64) {  // stage 3: merge lists 0..3 (36 keys)
      const unsigned* src = &mkeys[(t * 8) * NK];
      unsigned best[NK];
#pragma unroll
      for (int r = 0; r < NK; ++r) best[r] = 0u;
      for (int s = 0; s < 36; ++s) {
        unsigned cur_k = src[s];
#pragma unroll
        for (int q = 0; q < NK; ++q) {
          unsigned hi = best[q] > cur_k ? best[q] : cur_k;
          unsigned lo = best[q] > cur_k ? cur_k : best[q];
          best[q] = hi;
          cur_k = lo;
        }
      }
      size_t row = (size_t)b * NN + n0 + t;
#pragma unroll
      for (int r = 0; r < NK; ++r)
        candK[(size_t)(seg * NK + r) * NROW + row] = best[r];
    }
  } else {
    // ---- k3 role: 49 blocks/XCD; P,Q = bf16((hn @ gcwb^T) * norm), 24 chunks ----
    int jj = j / 5;  // 0..48
    int n0 = jj * 64;
    int n = n0 + wg * 16 + l15;
    short8 bfr[6];
    {
      const short8* brow = (const short8*)(hb + (size_t)n * NC + l4 * 8);
#pragma unroll
      for (int ks = 0; ks < 6; ++ks) bfr[ks] = brow[ks * 4];
    }
    float nrm = norm[(size_t)b * NN + n];
    size_t orow = (size_t)b * NN + n;
    const char* wB = (const char*)gcwb;

    if (stg) { gload16(wB + gA, abuf[0] + LA); gload16(wB + gB, abuf[0] + LB); }
    int cur = 0;
    for (int ch = 0; ch < 24; ++ch) {
      int nxt = cur + 1 == 3 ? 0 : cur + 1;
      if (ch < 23) {
        const char* src = wB + (size_t)(ch + 1) * 12288;
        char* dl = &abuf[nxt][0];
        if (stg) { gload16(src + gA, dl + LA); gload16(src + gB, dl + LB); }
        asm volatile("s_waitcnt vmcnt(3)" ::: "memory");  // tolerate 1 store in flight
      } else {
        asm volatile("s_waitcnt vmcnt(0)" ::: "memory");
      }
      __builtin_amdgcn_s_barrier();
      __builtin_amdgcn_sched_barrier(0);
      const char* lb = &abuf[cur][0];
      f32x4 acc = {0.f, 0.f, 0.f, 0.f};
#pragma unroll
      for (int ks = 0; ks < 6; ++ks) {
        short8 af = *(const short8*)&lb[dso[ks]];
        acc = __builtin_amdgcn_mfma_f32_16x16x32_bf16(af, bfr[ks], acc, 0, 0, 0);
      }
      int o = ch * 32 + sub * 16 + l4 * 4;
      f32x4 st = acc * nrm;
      unsigned short* dst = (o < NCH) ? P : Q;
      int oo = (o < NCH) ? o : o - NCH;
      uint2 u;
      u.x = (unsigned)f2bf(st[0]) | ((unsigned)f2bf(st[1]) << 16);
      u.y = (unsigned)f2bf(st[2]) | ((unsigned)f2bf(st[3]) << 16);
      *(uint2*)&dst[orow * NCH + oo] = u;
      cur = nxt;
    }
  }
}

// ---------- K2b: merge 4x9 keys/row -> final top-9 indices ----------
__global__ __launch_bounds__(BDIM) void k2b_merge(const unsigned* __restrict__ candK,
                                                  int* __restrict__ idxo) {
  int row = blockIdx.x * BDIM + threadIdx.x;
  unsigned tk[NK];
#pragma unroll
  for (int r = 0; r < NK; ++r) tk[r] = 0u;
  for (int s = 0; s < 4 * NK; ++s) {
    unsigned cur = candK[(size_t)s * NROW + row];
#pragma unroll
    for (int j = 0; j < NK; ++j) {
      unsigned hi = tk[j] > cur ? tk[j] : cur;
      unsigned lo = tk[j] > cur ? cur : tk[j];
      tk[j] = hi;
      cur = lo;
    }
  }
#pragma unroll
  for (int r = 0; r < NK; ++r)
    idxo[(size_t)row * NK + r] = 4095 - (int)(tk[r] & 4095u);
}

// ---------- K4: batch->XCD-pinned gather-max + BN2 + gelu, bf16 out ----------
__global__ __launch_bounds__(BDIM) void k4_gathermax(
    const unsigned short* __restrict__ P, const unsigned short* __restrict__ Q,
    const int* __restrict__ idx, const float* __restrict__ sc2,
    const float* __restrict__ sh2, unsigned short* __restrict__ mbh) {
  int t = threadIdx.x;
  int lane = t & 63, wv = t >> 6;
  int b = blockIdx.x & 7;                      // batch == XCD (L2 pin for Q slab)
  int n = (int)(blockIdx.x >> 3) * 4 + wv;     // 0..3135
  size_t row = (size_t)b * NN + n;
  const int* ip = idx + row * NK;
  int id[NK];
#pragma unroll
  for (int k = 0; k < NK; ++k) id[k] = ip[k];
  const unsigned short* Qb = Q + (size_t)b * NN * NCH;
  const unsigned short* Pr = P + row * NCH;
  const unsigned short* Qr = Qb + (size_t)n * NCH;
#pragma unroll
  for (int j = 0; j < 3; ++j) {
    int o = j * 128 + lane * 2;
    float mx0 = -1e30f, mx1 = -1e30f;
#pragma unroll
    for (int k = 0; k < NK; ++k) {
      unsigned g = *(const unsigned*)&Qb[(size_t)id[k] * NCH + o];
      mx0 = fmaxf(mx0, bf2f(g & 0xffffu));
      mx1 = fmaxf(mx1, bf2f(g >> 16));
    }
    unsigned pv = *(const unsigned*)&Pr[o];
    unsigned qv = *(const unsigned*)&Qr[o];
    float2 ss = *(const float2*)&sc2[o];
    float2 hh = *(const float2*)&sh2[o];
    float e0 = bf2f(pv & 0xffffu) - bf2f(qv & 0xffffu) + mx0;
    float e1 = bf2f(pv >> 16) - bf2f(qv >> 16) + mx1;
    float y0 = e0 * ss.x + hh.x;
    float y1 = e1 * ss.y + hh.y;
    float ge0 = 0.5f * y0 * (1.f + erff(y0 * 0.70710678118654752f));
    float ge1 = 0.5f * y1 * (1.f + erff(y1 * 0.70710678118654752f));
    *(unsigned*)&mbh[row * NCH + o] =
        (unsigned)f2bf(ge0) | ((unsigned)f2bf(ge1) << 16);
  }
}

// ---------- K5: out = BN3(m @ fc2_w^T) + x via MFMA, direct [c][n] store ----------
__global__ __launch_bounds__(BDIM) void k5_mfma(
    const unsigned short* __restrict__ mbh, const unsigned short* __restrict__ fc2b,
    const float* __restrict__ sc3, const float* __restrict__ sh3,
    const float* __restrict__ x, float* __restrict__ out) {
  __shared__ __align__(16) char abuf[2][24576];
  int t = threadIdx.x;
  int bid = blockIdx.x;
  int b = bid / 147;
  int rem = bid % 147;
  int n0 = (rem / 3) * 64;
  int oc = rem % 3;
  int lane = t & 63, w = t >> 6;
  int l15 = lane & 15, l4 = lane >> 4;
  int n = n0 + w * 16 + l15;
  short8 bfr[12];
  {
    const short8* brow = (const short8*)(mbh + (size_t)(b * NN + n) * NCH + l4 * 8);
#pragma unroll
    for (int kh = 0; kh < 2; ++kh)
#pragma unroll
      for (int ks = 0; ks < 6; ++ks) bfr[kh * 6 + ks] = brow[kh * 24 + ks * 4];
  }
  f32x4 acc[4];
#pragma unroll
  for (int sub = 0; sub < 4; ++sub) acc[sub] = {0.f, 0.f, 0.f, 0.f};

  const char* wt = (const char*)fc2b + (size_t)oc * 2 * 24576;
  stage_tile(wt, abuf[0], t);
  __syncthreads();
  for (int kh = 0; kh < 2; ++kh) {
    if (kh == 0) stage_tile(wt + 24576, abuf[1], t);
#pragma unroll
    for (int sub = 0; sub < 4; ++sub) {
      int r_ = sub * 16 + l15;
      int rbase = r_ * 384, sw = (r_ & 7) << 4;
#pragma unroll
      for (int ks = 0; ks < 6; ++ks) {
        short8 af = *(const short8*)&abuf[kh][rbase + ((ks * 64 + l4 * 16) ^ sw)];
        acc[sub] = __builtin_amdgcn_mfma_f32_16x16x32_bf16(af, bfr[kh * 6 + ks],
                                                           acc[sub], 0, 0, 0);
      }
    }
    __syncthreads();
  }
  const float* xb_ = x + (size_t)b * NC * NN;
  float* ob = out + (size_t)b * NC * NN;
#pragma unroll
  for (int sub = 0; sub < 4; ++sub) {
    int c4 = oc * 64 + sub * 16 + l4 * 4;
    float s_[4], h_[4];
    *(float4*)s_ = *(const float4*)&sc3[c4];
    *(float4*)h_ = *(const float4*)&sh3[c4];
#pragma unroll
    for (int r = 0; r < 4; ++r) {
      size_t off = (size_t)(c4 + r) * NN + n;
      ob[off] = acc[sub][r] * s_[r] + h_[r] + xb_[off];
    }
  }
}

extern "C" void kernel_launch(void* const* d_in, const int* in_sizes, int n_in,
                              void* d_out, int out_size, void* d_ws, size_t ws_size,
                              hipStream_t stream) {
  const float* x = (const float*)d_in[0];
  const float* fc1_w = (const float*)d_in[1];
  const float* fc1_b = (const float*)d_in[2];
  const float* bn1_g = (const float*)d_in[3];
  const float* bn1_b = (const float*)d_in[4];
  const float* bn1_m = (const float*)d_in[5];
  const float* bn1_v = (const float*)d_in[6];
  const float* gc_w = (const float*)d_in[7];
  const float* gc_b = (const float*)d_in[8];
  const float* bn2_g = (const float*)d_in[9];
  const float* bn2_b = (const float*)d_in[10];
  const float* bn2_m = (const float*)d_in[11];
  const float* bn2_v = (const float*)d_in[12];
  const float* fc2_w = (const float*)d_in[13];
  const float* fc2_b = (const float*)d_in[14];
  const float* bn3_g = (const float*)d_in[15];
  const float* bn3_b = (const float*)d_in[16];
  const float* bn3_m = (const float*)d_in[17];
  const float* bn3_v = (const float*)d_in[18];

  size_t nrow = (size_t)NROW;
  size_t npq = (size_t)NB * NN * NCH;
  size_t nhb = (size_t)NB * NN * NC;
  unsigned short* Pb = (unsigned short*)d_ws;
  unsigned short* Qb = Pb + npq;
  unsigned short* mbh = Qb + npq;
  float* norm = (float*)(mbh + npq);
  int* idx = (int*)(norm + nrow);
  unsigned short* hnb = (unsigned short*)(idx + nrow * NK);
  unsigned short* gcwb = hnb + nhb;
  unsigned short* fc1b = gcwb + 768 * NC;
  unsigned short* fc2b = fc1b + NC * NC;
  unsigned* candK = (unsigned*)(fc2b + NC * NCH);
  float* sc1 = (float*)(candK + 4 * NK * nrow);
  float* sh1 = sc1 + NC;
  float* sc2 = sh1 + NC;
  float* sh2 = sc2 + NCH;
  float* sc3 = sh2 + NCH;
  float* sh3 = sc3 + NC;

  k0_convw<<<252, BDIM, 0, stream>>>(gc_w, fc1_w, fc2_w, gcwb, fc1b, fc2b);
  k0b_params<<<1, 384, 0, stream>>>(fc1_b, bn1_g, bn1_b, bn1_m, bn1_v, gc_b,
                                    bn2_g, bn2_b, bn2_m, bn2_v, fc2_b, bn3_g,
                                    bn3_b, bn3_m, bn3_v, sc1, sh1, sc2, sh2,
                                    sc3, sh3);
  k1_mfma<<<NB * 49, BDIM, 0, stream>>>(x, fc1b, sc1, sh1, hnb, norm);
  k23_fused<<<NB * 245, 512, 0, stream>>>(hnb, norm, gcwb, candK, Pb, Qb);
  k2b_merge<<<NROW / BDIM, BDIM, 0, stream>>>(candK, idx);
  k4_gathermax<<<(NB * NN) / 4, BDIM, 0, stream>>>(Pb, Qb, idx, sc2, sh2, mbh);
  k5_mfma<<<NB * 147, BDIM, 0, stream>>>(mbh, fc2b, sc3, sh3, x, (float*)d_out);
}